// Round 8
// baseline (946.692 us; speedup 1.0000x reference)
//
#include <hip/hip_runtime.h>
#include <hip/hip_bf16.h>
#include <stdint.h>

#define H       256
#define INDIM   64
#define TSTEPS  128
#define BATCH   2048
#define MROWS   16
#define OUTD    4

typedef __attribute__((ext_vector_type(8))) short bf16x8;
typedef __attribute__((ext_vector_type(4))) float f32x4;

__device__ __forceinline__ short b2s(float x) {
  __hip_bfloat16 h = __float2bfloat16(x);
  return __builtin_bit_cast(short, h);
}

// [16][256] bf16 tile, XOR-granule swizzle on writes/reads (R3 family).
__device__ __forceinline__ int sidx(int m, int n) {
  return m * H + (n ^ ((m & 7) << 3));
}
__device__ __forceinline__ int wpk_slot(int lane) {
  return (((lane & 3) << 1) | ((lane >> 4) & 1)) |
         (((lane >> 2) & 3) << 3) | (((lane >> 5) & 1) << 5);
}

#define MFMA(a, b, c) __builtin_amdgcn_mfma_f32_16x16x32_bf16((a), (b), (c), 0, 0, 0)

// 128 blocks x 1024 threads: 16 waves/CU = 4 waves/SIMD (128-reg budget).
// M=16 MFMA fully dense (16 real batch rows, no lane duplication anywhere).
// Wave owns 16 N-cols -> weights = 16 bf16x8 frags = 64 regs; epilogue is
// 4 elems/lane with no permlane / masking (D-layout covers all 64 lanes).
__global__ __launch_bounds__(1024, 4) void node_kernel(
    const float* __restrict__ g_static, const float* __restrict__ g_times,
    const float* __restrict__ g_Win, const float* __restrict__ g_bin,
    const float* __restrict__ g_W1, const float* __restrict__ g_b1,
    const float* __restrict__ g_W2, const float* __restrict__ g_b2,
    const float* __restrict__ g_Wpk, const float* __restrict__ g_bpk,
    const float* __restrict__ g_Wpd, const float* __restrict__ g_bpd,
    float* __restrict__ g_out)
{
  __shared__ __align__(16) short arg_lds[MROWS * H];   // bf16 stage arg
  __shared__ __align__(16) short h1_lds[MROWS * H];    // bf16 tanh intermediate
  __shared__ __align__(16) short wpk_lds[8 * 64 * 8];  // Wpk B-frags
  __shared__ float h_lds[MROWS * H];                   // f32 h: init + final only
  __shared__ float s_lds[MROWS * INDIM];
  __shared__ float t_lds[TSTEPS];

  const int tid   = threadIdx.x;
  const int lane  = tid & 63;
  const int wid   = tid >> 6;        // 16 waves; wave owns N-cols [wid*16, wid*16+16)
  const int q     = lane >> 4;       // 0..3 (k-chunk / D-row group)
  const int c     = lane & 15;       // frag col
  const int b0    = blockIdx.x * MROWS;
  const int ncol0 = wid * 16;
  const int arow  = lane & 15;       // A-frag row — all 16 DISTINCT
  const int colu  = ncol0 + c;       // lane's owned absolute col

  if (tid < TSTEPS) t_lds[tid] = g_times[tid];

  const float b1u2 = 2.0f * g_b1[colu];   // pre-doubled for exp(2(v+b1))
  const float b2u  = g_b2[colu];
  const float bpkc = g_bpk[c & 3];
  const float bpdv = g_bpd[0];
  float wpd[4];
#pragma unroll
  for (int j = 0; j < 4; ++j) wpd[j] = g_Wpd[lane + 64 * j];

  // loop-invariant LDS element indices
  int ra[8], wa[4], ha[4];
#pragma unroll
  for (int kt = 0; kt < 8; ++kt) ra[kt] = sidx(arow, kt * 32 + q * 8);
#pragma unroll
  for (int r = 0; r < 4; ++r) {
    wa[r] = sidx(4 * q + r, colu);       // D row 4q+r, col colu — all lanes real
    ha[r] = (4 * q + r) * H + colu;
  }

  // ---- W1,W2 -> bf16 B-fragments in registers (64 regs) ----
  bf16x8 w1f[8], w2f[8];
#pragma unroll
  for (int kt = 0; kt < 8; ++kt) {
    const int kb = kt * 32 + q * 8;
    bf16x8 f1, f2;
#pragma unroll
    for (int u = 0; u < 8; ++u) {
      f1[u] = b2s(g_W1[(kb + u) * H + colu]);
      f2[u] = b2s(g_W2[(kb + u) * H + colu]);
    }
    w1f[kt] = f1;
    w2f[kt] = f2;
  }

  // ---- Wpk B-fragments -> LDS (wave 0; cols>=4 zero) ----
  if (wid == 0) {
    const int slot = wpk_slot(lane);
#pragma unroll
    for (int kt = 0; kt < 8; ++kt) {
      bf16x8 f;
#pragma unroll
      for (int u = 0; u < 8; ++u) {
        const int k = kt * 32 + q * 8 + u;
        f[u] = (c < OUTD) ? b2s(g_Wpk[k * OUTD + c]) : (short)0;
      }
      *(bf16x8*)(wpk_lds + kt * 512 + slot * 8) = f;
    }
  }

  // ---- h0 = static @ W_in + b_in (wave = row, lane = 4 cols) ----
  s_lds[tid] = g_static[(b0 + wid) * INDIM + lane];
  __syncthreads();
  {
    const int m  = wid;
    const int n0 = lane * 4;
    float a0 = g_bin[n0], a1 = g_bin[n0 + 1], a2 = g_bin[n0 + 2], a3 = g_bin[n0 + 3];
#pragma unroll 8
    for (int k = 0; k < INDIM; ++k) {
      const float sv = s_lds[m * INDIM + k];
      const f32x4 w = *(const f32x4*)(g_Win + k * H + n0);
      a0 += sv * w[0]; a1 += sv * w[1]; a2 += sv * w[2]; a3 += sv * w[3];
    }
    h_lds[m * H + n0] = a0;     h_lds[m * H + n0 + 1] = a1;
    h_lds[m * H + n0 + 2] = a2; h_lds[m * H + n0 + 3] = a3;
    arg_lds[sidx(m, n0)]     = b2s(a0);
    arg_lds[sidx(m, n0 + 1)] = b2s(a1);
    arg_lds[sidx(m, n0 + 2)] = b2s(a2);
    arg_lds[sidx(m, n0 + 3)] = b2s(a3);
  }
  __syncthreads();

  // h state in registers: lane holds rows 4q+r, col colu
  float hb[4];
#pragma unroll
  for (int r = 0; r < 4; ++r) hb[r] = h_lds[ha[r]];

  const int wslot = wpk_slot(lane);
  auto emit_pk = [&](int t) {
    if (wid == 0) {
      f32x4 acc = {0.f, 0.f, 0.f, 0.f};
#pragma unroll
      for (int kt = 0; kt < 8; ++kt) {
        const bf16x8 aA = *(const bf16x8*)(arg_lds + ra[kt]);
        const bf16x8 bW = *(const bf16x8*)(wpk_lds + kt * 512 + wslot * 8);
        acc = MFMA(aA, bW, acc);
      }
      if (c < OUTD) {
#pragma unroll
        for (int r = 0; r < 4; ++r)
          g_out[((size_t)(b0 + 4 * q + r) * TSTEPS + t) * OUTD + c] = acc[r] + bpkc;
      }
    }
  };

  emit_pk(0);

  const f32x4 vz = {0.f, 0.f, 0.f, 0.f};
  for (int t = 1; t < TSTEPS; ++t) {
    const float dt = t_lds[t] - t_lds[t - 1];
    const float s6 = dt * (1.0f / 6.0f);
    float ks[4];

#pragma unroll
    for (int ev = 0; ev < 4; ++ev) {
      // ---- phase 1: h1 = tanh(arg @ W1 + b1) ----
      {
        f32x4 A0 = vz, B0 = vz;   // 2 independent depth-4 chains
#pragma unroll
        for (int i = 0; i < 4; ++i) {
          const bf16x8 fA = *(const bf16x8*)(arg_lds + ra[i]);
          const bf16x8 fB = *(const bf16x8*)(arg_lds + ra[i + 4]);
          A0 = MFMA(fA, w1f[i], A0);
          B0 = MFMA(fB, w1f[i + 4], B0);
        }
#pragma unroll
        for (int r = 0; r < 4; ++r) {
          const float v  = A0[r] + B0[r];
          const float e  = __expf(__builtin_fmaf(2.0f, v, b1u2));
          const float th = 1.0f - __fdividef(2.0f, e + 1.0f);
          h1_lds[wa[r]] = b2s(th);
        }
      }
      __syncthreads();

      // ---- phase 2: k = h1 @ W2 + b2, RK4 update ----
      {
        f32x4 A0 = vz, B0 = vz;
#pragma unroll
        for (int i = 0; i < 4; ++i) {
          const bf16x8 fA = *(const bf16x8*)(h1_lds + ra[i]);
          const bf16x8 fB = *(const bf16x8*)(h1_lds + ra[i + 4]);
          A0 = MFMA(fA, w2f[i], A0);
          B0 = MFMA(fB, w2f[i + 4], B0);
        }
#pragma unroll
        for (int r = 0; r < 4; ++r) {
          const float kv = A0[r] + B0[r] + b2u;
          if (ev == 0)      ks[r] = kv;
          else if (ev == 3) ks[r] += kv;
          else              ks[r] += 2.0f * kv;
          if (ev < 3) {
            const float cc = (ev == 2) ? dt : 0.5f * dt;
            arg_lds[wa[r]] = b2s(__builtin_fmaf(cc, kv, hb[r]));
          } else {
            hb[r] = __builtin_fmaf(s6, ks[r], hb[r]);
            arg_lds[wa[r]] = b2s(hb[r]);
          }
        }
      }
      __syncthreads();
    }
    emit_pk(t);
  }

  // ---- pd = h_T @ W_pd + b_pd (wave w reduces row w) ----
#pragma unroll
  for (int r = 0; r < 4; ++r) h_lds[ha[r]] = hb[r];
  __syncthreads();
  {
    float p = 0.0f;
#pragma unroll
    for (int j = 0; j < 4; ++j) p += h_lds[wid * H + lane + 64 * j] * wpd[j];
#pragma unroll
    for (int m = 1; m < 64; m <<= 1) p += __shfl_xor(p, m);
    if (lane == 0) g_out[(size_t)BATCH * TSTEPS * OUTD + b0 + wid] = p + bpdv;
  }
}

extern "C" void kernel_launch(void* const* d_in, const int* in_sizes, int n_in,
                              void* d_out, int out_size, void* d_ws, size_t ws_size,
                              hipStream_t stream) {
  const float* g_static = (const float*)d_in[0];
  const float* g_times  = (const float*)d_in[1];
  const float* g_Win    = (const float*)d_in[2];
  const float* g_bin    = (const float*)d_in[3];
  const float* g_W1     = (const float*)d_in[4];
  const float* g_b1     = (const float*)d_in[5];
  const float* g_W2     = (const float*)d_in[6];
  const float* g_b2     = (const float*)d_in[7];
  const float* g_Wpk    = (const float*)d_in[8];
  const float* g_bpk    = (const float*)d_in[9];
  const float* g_Wpd    = (const float*)d_in[10];
  const float* g_bpd    = (const float*)d_in[11];

  node_kernel<<<dim3(BATCH / MROWS), dim3(1024), 0, stream>>>(
      g_static, g_times, g_Win, g_bin, g_W1, g_b1, g_W2, g_b2,
      g_Wpk, g_bpk, g_Wpd, g_bpd, (float*)d_out);
}

// Round 9
// 640.805 us; speedup vs baseline: 1.4773x; 1.4773x over previous
//
#include <hip/hip_runtime.h>
#include <hip/hip_bf16.h>
#include <stdint.h>

#define H       256
#define INDIM   64
#define TSTEPS  128
#define BATCH   2048
#define MROWS   8
#define OUTD    4

typedef __attribute__((ext_vector_type(8))) short bf16x8;
typedef __attribute__((ext_vector_type(4))) float f32x4;

__device__ __forceinline__ short b2s(float x) {
  __hip_bfloat16 h = __float2bfloat16(x);
  return __builtin_bit_cast(short, h);
}

// R3 swizzle. The ~4cy/ds_read_b128 "conflict" tax is intrinsic port
// accounting (1024B/wave / 256B/clk), invariant to layout (R4/R7/R8).
__device__ __forceinline__ int swz(int m, int n) {
  return (m * H + n) ^ ((m & 7) << 3);
}
__device__ __forceinline__ int wpk_slot(int lane) {
  return (((lane & 3) << 1) | ((lane >> 4) & 1)) |
         (((lane >> 2) & 3) << 3) | (((lane >> 5) & 1) << 5);
}

// lanes 0-31 keep a; lanes 32-63 receive b from (lane-32).
__device__ __forceinline__ float swap_hilo(float a, float b) {
#if __has_builtin(__builtin_amdgcn_permlane32_swap)
  typedef unsigned int u32x2 __attribute__((ext_vector_type(2)));
  u32x2 r = __builtin_amdgcn_permlane32_swap(
      __builtin_bit_cast(unsigned int, a),
      __builtin_bit_cast(unsigned int, b), false, false);
  return __builtin_bit_cast(float, r[0]);
#else
  float t = __shfl_xor(b, 32);
  return (threadIdx.x & 32) ? t : a;
#endif
}

#define MFMA(a, b, c) __builtin_amdgcn_mfma_f32_16x16x32_bf16((a), (b), (c), 0, 0, 0)

// lgkmcnt-only barrier: publishes LDS writes without the vmcnt(0) drain
// __syncthreads() forces (which serializes wave-0's emit_pk global stores
// into every phase). Stores drain in the background instead.
#define BAR() do {                                            \
    asm volatile("s_waitcnt lgkmcnt(0)" ::: "memory");        \
    __builtin_amdgcn_s_barrier();                             \
  } while (0)

__global__ __launch_bounds__(512, 1) void node_kernel(
    const float* __restrict__ g_static, const float* __restrict__ g_times,
    const float* __restrict__ g_Win, const float* __restrict__ g_bin,
    const float* __restrict__ g_W1, const float* __restrict__ g_b1,
    const float* __restrict__ g_W2, const float* __restrict__ g_b2,
    const float* __restrict__ g_Wpk, const float* __restrict__ g_bpk,
    const float* __restrict__ g_Wpd, const float* __restrict__ g_bpd,
    float* __restrict__ g_out)
{
  __shared__ __align__(16) short arg_lds[MROWS * H];
  __shared__ __align__(16) short h1_lds[MROWS * H];
  __shared__ __align__(16) short wpk_lds[8 * 64 * 8];
  __shared__ float h_lds[MROWS * H];
  __shared__ float s_lds[MROWS * INDIM];
  __shared__ float t_lds[TSTEPS];

  const int tid   = threadIdx.x;
  const int lane  = tid & 63;
  const int wid   = tid >> 6;
  const int g     = lane >> 4;
  const int c     = lane & 15;
  const int b0    = blockIdx.x * MROWS;
  const int ncol0 = wid * 32;
  const int am    = lane & 7;
  const int gg    = (lane >> 4) & 1;
  const int hh    = lane >> 5;
  const int colu  = ncol0 + 16 * hh + c;
  const int dm    = 4 * g;

  if (tid < TSTEPS) t_lds[tid] = g_times[tid];

  const float b1u2 = 2.0f * g_b1[colu];
  const float b2u  = g_b2[colu];
  const float bpkc = g_bpk[c & 3];
  const float bpdv = g_bpd[0];
  float wpd[4];
#pragma unroll
  for (int j = 0; j < 4; ++j) wpd[j] = g_Wpd[lane + 64 * j];

  int ra[8], wa[4], ha[4];
#pragma unroll
  for (int kt = 0; kt < 8; ++kt) ra[kt] = swz(am, kt * 32 + g * 8);
#pragma unroll
  for (int r = 0; r < 4; ++r) {
    wa[r] = swz(4 * gg + r, colu);
    ha[r] = (4 * gg + r) * H + colu;
  }

  // ---- W1,W2 -> bf16 B-fragments in registers (128 regs/lane) ----
  bf16x8 w1f[8][2], w2f[8][2];
#pragma unroll
  for (int kt = 0; kt < 8; ++kt) {
#pragma unroll
    for (int nt = 0; nt < 2; ++nt) {
      const int n  = ncol0 + nt * 16 + c;
      const int kb = kt * 32 + g * 8;
      bf16x8 f1, f2;
#pragma unroll
      for (int u = 0; u < 8; ++u) {
        f1[u] = b2s(g_W1[(kb + u) * H + n]);
        f2[u] = b2s(g_W2[(kb + u) * H + n]);
      }
      w1f[kt][nt] = f1;
      w2f[kt][nt] = f2;
    }
  }

  if (wid == 0) {
    const int slot = wpk_slot(lane);
#pragma unroll
    for (int kt = 0; kt < 8; ++kt) {
      bf16x8 f;
#pragma unroll
      for (int u = 0; u < 8; ++u) {
        const int k = kt * 32 + g * 8 + u;
        f[u] = (c < OUTD) ? b2s(g_Wpk[k * OUTD + c]) : (short)0;
      }
      *(bf16x8*)(wpk_lds + kt * 512 + slot * 8) = f;
    }
  }

  // ---- h0 = static @ W_in + b_in ----
  s_lds[tid] = g_static[(b0 + (tid >> 6)) * INDIM + (tid & 63)];
  __syncthreads();
  {
    const int m  = tid >> 6;
    const int n0 = (tid & 63) * 4;
    float a0 = g_bin[n0], a1 = g_bin[n0 + 1], a2 = g_bin[n0 + 2], a3 = g_bin[n0 + 3];
#pragma unroll 8
    for (int k = 0; k < INDIM; ++k) {
      const float sv = s_lds[m * INDIM + k];
      const f32x4 w = *(const f32x4*)(g_Win + k * H + n0);
      a0 += sv * w[0]; a1 += sv * w[1]; a2 += sv * w[2]; a3 += sv * w[3];
    }
    h_lds[m * H + n0] = a0;     h_lds[m * H + n0 + 1] = a1;
    h_lds[m * H + n0 + 2] = a2; h_lds[m * H + n0 + 3] = a3;
    arg_lds[swz(m, n0)]     = b2s(a0);
    arg_lds[swz(m, n0 + 1)] = b2s(a1);
    arg_lds[swz(m, n0 + 2)] = b2s(a2);
    arg_lds[swz(m, n0 + 3)] = b2s(a3);
  }
  __syncthreads();

  float hb[4];
#pragma unroll
  for (int r = 0; r < 4; ++r) hb[r] = h_lds[ha[r]];

  const int wslot = wpk_slot(lane);
  auto emit_pk = [&](int t) {
    if (wid == 0) {
      f32x4 acc = {0.f, 0.f, 0.f, 0.f};
#pragma unroll
      for (int kt = 0; kt < 8; ++kt) {
        const bf16x8 aA = *(const bf16x8*)(arg_lds + ra[kt]);
        const bf16x8 bW = *(const bf16x8*)(wpk_lds + kt * 512 + wslot * 8);
        acc = MFMA(aA, bW, acc);
      }
      if (g < 2 && c < OUTD) {
#pragma unroll
        for (int r = 0; r < 4; ++r)
          g_out[((size_t)(b0 + dm + r) * TSTEPS + t) * OUTD + c] = acc[r] + bpkc;
      }
    }
  };

  emit_pk(0);

  for (int t = 1; t < TSTEPS; ++t) {
    const float dt = t_lds[t] - t_lds[t - 1];
    const float s6 = dt * (1.0f / 6.0f);
    float ks[4];

#pragma unroll
    for (int ev = 0; ev < 4; ++ev) {
      // ---- phase 1: h1 = tanh(arg @ W1 + b1) ----
      f32x4 acc0a = {b1u2 * 0.0f, 0.f, 0.f, 0.f};  // (kept zero-init; bias post-swap)
      acc0a = f32x4{0.f, 0.f, 0.f, 0.f};
      f32x4 acc1a = {0.f, 0.f, 0.f, 0.f};
      f32x4 acc0b = {0.f, 0.f, 0.f, 0.f};
      f32x4 acc1b = {0.f, 0.f, 0.f, 0.f};
#pragma unroll
      for (int kt = 0; kt < 4; ++kt) {
        const bf16x8 aA = *(const bf16x8*)(arg_lds + ra[kt]);
        const bf16x8 aB = *(const bf16x8*)(arg_lds + ra[kt + 4]);
        acc0a = MFMA(aA, w1f[kt][0], acc0a);
        acc1a = MFMA(aA, w1f[kt][1], acc1a);
        acc0b = MFMA(aB, w1f[kt + 4][0], acc0b);
        acc1b = MFMA(aB, w1f[kt + 4][1], acc1b);
      }
      {
        const f32x4 S0 = acc0a + acc0b;
        const f32x4 S1 = acc1a + acc1b;
#pragma unroll
        for (int r = 0; r < 4; ++r) {
          const float v  = swap_hilo(S0[r], S1[r]);
          const float e  = __expf(__builtin_fmaf(2.0f, v, b1u2));
          const float th = __builtin_fmaf(-2.0f, __builtin_amdgcn_rcpf(e + 1.0f), 1.0f);
          h1_lds[wa[r]] = b2s(th);
        }
      }
      BAR();

      // ---- phase 2: k = h1 @ W2 + b2, RK4 update ----
      f32x4 k0a = {0.f, 0.f, 0.f, 0.f};
      f32x4 k1a = {0.f, 0.f, 0.f, 0.f};
      f32x4 k0b = {0.f, 0.f, 0.f, 0.f};
      f32x4 k1b = {0.f, 0.f, 0.f, 0.f};
#pragma unroll
      for (int kt = 0; kt < 4; ++kt) {
        const bf16x8 aA = *(const bf16x8*)(h1_lds + ra[kt]);
        const bf16x8 aB = *(const bf16x8*)(h1_lds + ra[kt + 4]);
        k0a = MFMA(aA, w2f[kt][0], k0a);
        k1a = MFMA(aA, w2f[kt][1], k1a);
        k0b = MFMA(aB, w2f[kt + 4][0], k0b);
        k1b = MFMA(aB, w2f[kt + 4][1], k1b);
      }
      {
        const f32x4 S0 = k0a + k0b;
        const f32x4 S1 = k1a + k1b;
#pragma unroll
        for (int r = 0; r < 4; ++r) {
          const float kv = swap_hilo(S0[r], S1[r]) + b2u;
          if (ev == 0)      ks[r] = kv;
          else if (ev == 3) ks[r] += kv;
          else              ks[r] += 2.0f * kv;
          if (ev < 3) {
            const float cc = (ev == 2) ? dt : 0.5f * dt;
            arg_lds[wa[r]] = b2s(__builtin_fmaf(cc, kv, hb[r]));
          } else {
            hb[r] = __builtin_fmaf(s6, ks[r], hb[r]);
            arg_lds[wa[r]] = b2s(hb[r]);
          }
        }
      }
      BAR();
    }
    emit_pk(t);
  }

  // ---- pd = h_T @ W_pd + b_pd ----
#pragma unroll
  for (int r = 0; r < 4; ++r) h_lds[ha[r]] = hb[r];
  __syncthreads();
  {
    float p = 0.0f;
#pragma unroll
    for (int j = 0; j < 4; ++j) p += h_lds[wid * H + lane + 64 * j] * wpd[j];
#pragma unroll
    for (int m = 1; m < 64; m <<= 1) p += __shfl_xor(p, m);
    if (lane == 0) g_out[(size_t)BATCH * TSTEPS * OUTD + b0 + wid] = p + bpdv;
  }
}

extern "C" void kernel_launch(void* const* d_in, const int* in_sizes, int n_in,
                              void* d_out, int out_size, void* d_ws, size_t ws_size,
                              hipStream_t stream) {
  const float* g_static = (const float*)d_in[0];
  const float* g_times  = (const float*)d_in[1];
  const float* g_Win    = (const float*)d_in[2];
  const float* g_bin    = (const float*)d_in[3];
  const float* g_W1     = (const float*)d_in[4];
  const float* g_b1     = (const float*)d_in[5];
  const float* g_W2     = (const float*)d_in[6];
  const float* g_b2     = (const float*)d_in[7];
  const float* g_Wpk    = (const float*)d_in[8];
  const float* g_bpk    = (const float*)d_in[9];
  const float* g_Wpd    = (const float*)d_in[10];
  const float* g_bpd    = (const float*)d_in[11];

  node_kernel<<<dim3(BATCH / MROWS), dim3(512), 0, stream>>>(
      g_static, g_times, g_Win, g_bin, g_W1, g_b1, g_W2, g_b2,
      g_Wpk, g_bpk, g_Wpd, g_bpd, (float*)d_out);
}